// Round 3
// baseline (143.283 us; speedup 1.0000x reference)
//
#include <hip/hip_runtime.h>

#define NI 4096
#define NH 8192
#define NO 2048

typedef float  f4 __attribute__((ext_vector_type(4)));
typedef unsigned short u16x8 __attribute__((ext_vector_type(8)));
typedef unsigned int   u32x2 __attribute__((ext_vector_type(2)));

__device__ __forceinline__ float apply_act(float x, int id) {
    switch (id) {
        case 0:  return x;
        case 1:  return x >= 0.f ? x : 0.01f * x;   // leaky_relu
        case 2:  return fmaxf(x, 0.f);              // relu
        case 3:  return 1.f / (1.f + expf(-x));     // sigmoid
        default: return tanhf(x);                   // tanh
    }
}

// round-to-nearest-even fp32 -> bf16 (as uint16 payload)
__device__ __forceinline__ unsigned int f2bf(float f) {
    unsigned int u = __float_as_uint(f);
    return (u + 0x7FFFu + ((u >> 16) & 1u)) >> 16;
}
__device__ __forceinline__ float bf2f(unsigned int b) {
    return __uint_as_float(b << 16);
}

// One 64-lane wave computes dot(Wrow, x) in fp32. NT = non-temporal (stream).
template <bool NT>
__device__ __forceinline__ float wave_dot(const float* __restrict__ Wrow,
                                          const float* __restrict__ x,
                                          int K, int lane) {
    const f4* __restrict__ W4 = (const f4*)Wrow;
    const f4* __restrict__ x4 = (const f4*)x;
    float acc = 0.f;
    const int n4 = K >> 2;
    #pragma unroll 4
    for (int i = lane; i < n4; i += 64) {
        f4 w = NT ? __builtin_nontemporal_load(W4 + i) : W4[i];
        f4 v = x4[i];
        acc = fmaf(w.x, v.x, acc);
        acc = fmaf(w.y, v.y, acc);
        acc = fmaf(w.z, v.z, acc);
        acc = fmaf(w.w, v.w, acc);
    }
    #pragma unroll
    for (int off = 32; off; off >>= 1) acc += __shfl_xor(acc, off, 64);
    return acc;
}

// Wave dot with bf16 weight row (ushort8 = 16B loads), fp32 x and accum.
__device__ __forceinline__ float wave_dot_bf(const unsigned short* __restrict__ Wrow,
                                             const float* __restrict__ x,
                                             int K, int lane) {
    const u16x8* __restrict__ W8 = (const u16x8*)Wrow;
    const f4* __restrict__ x4 = (const f4*)x;
    float acc = 0.f;
    const int n8 = K >> 3;
    #pragma unroll 4
    for (int i = lane; i < n8; i += 64) {
        u16x8 w = W8[i];
        f4 va = x4[2 * i];
        f4 vb = x4[2 * i + 1];
        acc = fmaf(bf2f(w[0]), va.x, acc);
        acc = fmaf(bf2f(w[1]), va.y, acc);
        acc = fmaf(bf2f(w[2]), va.z, acc);
        acc = fmaf(bf2f(w[3]), va.w, acc);
        acc = fmaf(bf2f(w[4]), vb.x, acc);
        acc = fmaf(bf2f(w[5]), vb.y, acc);
        acc = fmaf(bf2f(w[6]), vb.z, acc);
        acc = fmaf(bf2f(w[7]), vb.w, acc);
    }
    #pragma unroll
    for (int off = 32; off; off >>= 1) acc += __shfl_xor(acc, off, 64);
    return acc;
}

// Single block: flags[i] = any(vec_i != 0)
__global__ __launch_bounds__(256) void k_flags(const float* __restrict__ xin,
                                               const float* __restrict__ a0,
                                               const float* __restrict__ o0,
                                               int* __restrict__ flags) {
    __shared__ int s[3];
    int t = threadIdx.x;
    if (t < 3) s[t] = 0;
    __syncthreads();
    int f0 = 0, f1 = 0, f2 = 0;
    for (int i = t; i < NI; i += 256) f0 |= (xin[i] != 0.f);
    for (int i = t; i < NH; i += 256) f1 |= (a0[i]  != 0.f);
    for (int i = t; i < NO; i += 256) f2 |= (o0[i]  != 0.f);
    if (f0) atomicOr(&s[0], 1);
    if (f1) atomicOr(&s[1], 1);
    if (f2) atomicOr(&s[2], 1);
    __syncthreads();
    if (t < 3) flags[t] = s[t];
}

// Fused: c_h[m] = i2h·x + o2h·o0 (loop-invariant) + step-1 epilogue.
__global__ __launch_bounds__(256) void k_h_init(const float* __restrict__ W_i2h,
                                                const float* __restrict__ W_o2h,
                                                const float* __restrict__ W_h2h,
                                                const float* __restrict__ xin,
                                                const float* __restrict__ o0,
                                                const float* __restrict__ a0,
                                                const float* __restrict__ resp,
                                                const float* __restrict__ bias,
                                                const int* __restrict__ ids,
                                                const int* __restrict__ flags,
                                                float* __restrict__ c_h,
                                                float* __restrict__ act_a) {
    int wave = threadIdx.x >> 6;
    int lane = threadIdx.x & 63;
    int m = blockIdx.x * 4 + wave;
    float c = 0.f;
    if (flags[0]) c += wave_dot<true>(W_i2h + (size_t)m * NI, xin, NI, lane);
    if (flags[2]) c += wave_dot<true>(W_o2h + (size_t)m * NO, o0,  NO, lane);
    float d = 0.f;
    if (flags[1]) d = wave_dot<false>(W_h2h + (size_t)m * NH, a0, NH, lane);
    if (lane == 0) {
        c_h[m] = c;
        act_a[m] = apply_act(fmaf(resp[m], c + d, bias[m]), ids[m]);
    }
}

// Step 2 + convert: dot in fp32 (NT stream of W_h2h) while writing a rounded
// bf16 copy of the row into Wb (normal stores -> L3-resident for step 3).
__global__ __launch_bounds__(256) void k_step2_conv(const float* __restrict__ W_h2h,
                                                    const float* __restrict__ x,
                                                    const float* __restrict__ c_h,
                                                    const float* __restrict__ resp,
                                                    const float* __restrict__ bias,
                                                    const int* __restrict__ ids,
                                                    float* __restrict__ out,
                                                    unsigned short* __restrict__ Wb) {
    int wave = threadIdx.x >> 6;
    int lane = threadIdx.x & 63;
    int m = blockIdx.x * 4 + wave;
    const f4* __restrict__ W4 = (const f4*)(W_h2h + (size_t)m * NH);
    const f4* __restrict__ x4 = (const f4*)x;
    u32x2* __restrict__ B2 = (u32x2*)(Wb + (size_t)m * NH);
    float acc = 0.f;
    #pragma unroll 4
    for (int i = lane; i < NH / 4; i += 64) {
        f4 w = __builtin_nontemporal_load(W4 + i);
        f4 v = x4[i];
        acc = fmaf(w.x, v.x, acc);
        acc = fmaf(w.y, v.y, acc);
        acc = fmaf(w.z, v.z, acc);
        acc = fmaf(w.w, v.w, acc);
        u32x2 b;
        b.x = f2bf(w.x) | (f2bf(w.y) << 16);
        b.y = f2bf(w.z) | (f2bf(w.w) << 16);
        B2[i] = b;
    }
    #pragma unroll
    for (int off = 32; off; off >>= 1) acc += __shfl_xor(acc, off, 64);
    if (lane == 0) {
        float pre = fmaf(resp[m], c_h[m] + acc, bias[m]);
        out[m] = apply_act(pre, ids[m]);
    }
}

// Step 3: bf16 weights (half the bytes, hopefully L3-hot). Reversed order.
__global__ __launch_bounds__(256) void k_step3_bf(const unsigned short* __restrict__ Wb,
                                                  const float* __restrict__ x,
                                                  const float* __restrict__ c_h,
                                                  const float* __restrict__ resp,
                                                  const float* __restrict__ bias,
                                                  const int* __restrict__ ids,
                                                  float* __restrict__ out) {
    int wave = threadIdx.x >> 6;
    int lane = threadIdx.x & 63;
    int m = (NH - 1) - (blockIdx.x * 4 + wave);
    float dot = wave_dot_bf(Wb + (size_t)m * NH, x, NH, lane);
    if (lane == 0) {
        float pre = fmaf(resp[m], c_h[m] + dot, bias[m]);
        out[m] = apply_act(pre, ids[m]);
    }
}

// fp32 fallback step (used when ws is too small for the bf16 copy)
template <int REV>
__global__ __launch_bounds__(256) void k_step(const float* __restrict__ W_h2h,
                                              const float* __restrict__ x,
                                              const float* __restrict__ c_h,
                                              const float* __restrict__ resp,
                                              const float* __restrict__ bias,
                                              const int* __restrict__ ids,
                                              float* __restrict__ out) {
    int wave = threadIdx.x >> 6;
    int lane = threadIdx.x & 63;
    int m = blockIdx.x * 4 + wave;
    if (REV) m = (NH - 1) - m;
    float dot = wave_dot<false>(W_h2h + (size_t)m * NH, x, NH, lane);
    if (lane == 0) {
        float pre = fmaf(resp[m], c_h[m] + dot, bias[m]);
        out[m] = apply_act(pre, ids[m]);
    }
}

// Output layer: all weights single-use -> non-temporal.
__global__ __launch_bounds__(256) void k_final(const float* __restrict__ W_i2o,
                                               const float* __restrict__ W_o2o,
                                               const float* __restrict__ W_h2o,
                                               const float* __restrict__ xin,
                                               const float* __restrict__ o0,
                                               const float* __restrict__ act,
                                               const float* __restrict__ resp,
                                               const float* __restrict__ bias,
                                               const int* __restrict__ ids,
                                               const int* __restrict__ flags,
                                               float* __restrict__ out) {
    int wave = threadIdx.x >> 6;
    int lane = threadIdx.x & 63;
    int m = blockIdx.x * 4 + wave;
    float dot = wave_dot<true>(W_h2o + (size_t)m * NH, act, NH, lane);
    if (flags[0]) dot += wave_dot<true>(W_i2o + (size_t)m * NI, xin, NI, lane);
    if (flags[2]) dot += wave_dot<true>(W_o2o + (size_t)m * NO, o0,  NO, lane);
    if (lane == 0) {
        float pre = fmaf(resp[m], dot, bias[m]);
        out[m] = apply_act(pre, ids[m]);
    }
}

extern "C" void kernel_launch(void* const* d_in, const int* in_sizes, int n_in,
                              void* d_out, int out_size, void* d_ws, size_t ws_size,
                              hipStream_t stream) {
    const float* inputs   = (const float*)d_in[0];
    const float* W_i2h    = (const float*)d_in[1];
    const float* W_h2h    = (const float*)d_in[2];
    const float* W_o2h    = (const float*)d_in[3];
    const float* W_i2o    = (const float*)d_in[4];
    const float* W_h2o    = (const float*)d_in[5];
    const float* W_o2o    = (const float*)d_in[6];
    const float* h_resp   = (const float*)d_in[7];
    const float* h_bias   = (const float*)d_in[8];
    const float* o_resp   = (const float*)d_in[9];
    const float* o_bias   = (const float*)d_in[10];
    const float* activs0  = (const float*)d_in[11];
    const float* outputs0 = (const float*)d_in[12];
    const int*   h_ids    = (const int*)d_in[13];
    const int*   o_ids    = (const int*)d_in[14];

    float* ws    = (float*)d_ws;
    float* c_h   = ws;            // NH floats
    float* act_a = ws + NH;       // NH floats
    float* act_b = ws + 2 * NH;   // NH floats
    int*   flags = (int*)(ws + 3 * NH);   // 3 ints (+pad)

    size_t bf_off = (((size_t)(3 * NH + 4) * sizeof(float)) + 255) & ~(size_t)255;
    unsigned short* Wb = (unsigned short*)((char*)d_ws + bf_off);
    bool use_bf = ws_size >= bf_off + (size_t)NH * NH * sizeof(unsigned short);

    k_flags<<<1, 256, 0, stream>>>(inputs, activs0, outputs0, flags);

    k_h_init<<<NH / 4, 256, 0, stream>>>(W_i2h, W_o2h, W_h2h, inputs, outputs0,
                                         activs0, h_resp, h_bias, h_ids, flags,
                                         c_h, act_a);
    if (use_bf) {
        k_step2_conv<<<NH / 4, 256, 0, stream>>>(W_h2h, act_a, c_h, h_resp, h_bias,
                                                 h_ids, act_b, Wb);
        k_step3_bf<<<NH / 4, 256, 0, stream>>>(Wb, act_b, c_h, h_resp, h_bias,
                                               h_ids, act_a);
    } else {
        k_step<0><<<NH / 4, 256, 0, stream>>>(W_h2h, act_a, c_h, h_resp, h_bias,
                                              h_ids, act_b);
        k_step<1><<<NH / 4, 256, 0, stream>>>(W_h2h, act_b, c_h, h_resp, h_bias,
                                              h_ids, act_a);
    }

    k_final<<<NO / 4, 256, 0, stream>>>(W_i2o, W_o2o, W_h2o, inputs, outputs0, act_a,
                                        o_resp, o_bias, o_ids, flags, (float*)d_out);
}